// Round 8
// baseline (1363.336 us; speedup 1.0000x reference)
//
#include <hip/hip_runtime.h>
#include <hip/hip_bf16.h>

typedef __hip_bfloat16 bf16;
typedef short v8s __attribute__((ext_vector_type(8)));
typedef float v4f __attribute__((ext_vector_type(4)));
typedef unsigned long long u64;

#define BATCH 256
#define SEQ 64
#define INPUT 512
#define HIDDEN 1024
#define CLASSES 1000

// ============================================================================
// Fragment-linear layouts (bf16):
//   A-chunk (16 m x 32 k): chunk[lane*8+j] = A[m16*16+(lane&15)][k32*32+(lane>>4)*8+j]
//   B-chunk (16 n x 32 k): chunk[lane*8+j] = W[k32*32+(lane>>4)*8+j][ncol]
// Unified per-step A staging (the K axis is ONE buffer per layer per step):
//   S1[t]: [m16(16)][k32(48)][512]  chunks 0..15 = x(t), 16..47 = h1(t-1)
//   S2[t]: [m16(16)][k32(64)][512]  chunks 0..31 = h1(t), 32..63 = h2(t-1)
//   Producers write h directly into consumer staging slots (write-through).
// Bf:  [hb(128)][n16l(2)][k32(NT)][512]  K-order matches S1/S2.
// Wof: [n16(64)][k32(32)][512]
// ============================================================================

#define STR1 ((size_t)16 * 48 * 512)
#define STR2 ((size_t)16 * 64 * 512)

__global__ __launch_bounds__(256) void conv_x(const float* __restrict__ x,
                                              bf16* __restrict__ S1) {
    int gid = blockIdx.x * 256 + threadIdx.x;
    int lane = gid & 63;
    int k32 = (gid >> 6) & 15;
    int m16 = (gid >> 10) & 15;
    int tt  = gid >> 14;
    int row = lane & 15, quad = lane >> 4;
    int b_ = m16 * 16 + row;
    int k  = k32 * 32 + quad * 8;
    const float* src = x + ((size_t)(b_ * SEQ + tt) * INPUT + k);
    float4 v0 = *(const float4*)src;
    float4 v1 = *(const float4*)(src + 4);
    bf16 o[8] = {__float2bfloat16(v0.x), __float2bfloat16(v0.y),
                 __float2bfloat16(v0.z), __float2bfloat16(v0.w),
                 __float2bfloat16(v1.x), __float2bfloat16(v1.y),
                 __float2bfloat16(v1.z), __float2bfloat16(v1.w)};
    bf16* dst = S1 + (size_t)tt * STR1 + (size_t)(m16 * 48 + k32) * 512 + lane * 8;
    *(v8s*)dst = *(v8s*)o;
}

// [Wfirst;Wsecond] fp32 -> Bf slices. grid (Ktot/64, 128, 2), block 256.
__global__ __launch_bounds__(256) void build_bf(const float* __restrict__ Wfirst,
                                                const float* __restrict__ Wsecond,
                                                int K0, int NT,
                                                bf16* __restrict__ dst) {
    __shared__ float tile[64][17];
    const int kt = blockIdx.x, hb = blockIdx.y, n16l = blockIdx.z;
    const int k0 = kt * 64;
    const int tid = threadIdx.x;
#pragma unroll
    for (int i = 0; i < 4; i++) {
        int idx = tid + i * 256;
        int c = idx & 15, kl = idx >> 4;
        int k = k0 + kl;
        int srccol = (n16l * 2 + (c >> 3)) * 1024 + hb * 8 + (c & 7);
        float v = (k < K0) ? Wfirst[(size_t)k * 4096 + srccol]
                           : Wsecond[(size_t)(k - K0) * 4096 + srccol];
        tile[kl][c] = v;
    }
    __syncthreads();
    if (tid < 128) {
        int k32l = tid >> 6, l = tid & 63;
        bf16 o[8];
#pragma unroll
        for (int j = 0; j < 8; j++)
            o[j] = __float2bfloat16(tile[k32l * 32 + (l >> 4) * 8 + j][l & 15]);
        *(v8s*)(dst + ((size_t)(hb * 2 + n16l) * NT + kt * 2 + k32l) * 512 + l * 8) = *(v8s*)o;
    }
}

__global__ __launch_bounds__(256) void build_wof(const float* __restrict__ Wo,
                                                 bf16* __restrict__ dst) {
    __shared__ float tile[64][17];
    const int h16 = blockIdx.y, kt = blockIdx.x;
    const int k0 = kt * 64, nb = h16 * 16;
    const int tid = threadIdx.x;
#pragma unroll
    for (int i = 0; i < 4; i++) {
        int idx = tid + i * 256;
        int kl = idx >> 4, c = idx & 15;
        int k = k0 + kl;
        float v = (nb + c < CLASSES) ? Wo[(size_t)k * CLASSES + nb + c] : 0.f;
        tile[kl][c] = v;
    }
    __syncthreads();
    if (tid < 128) {
        int k32l = tid >> 6, l = tid & 63;
        int col = l & 15, quad = l >> 4;
        bf16 o[8];
#pragma unroll
        for (int j = 0; j < 8; j++)
            o[j] = __float2bfloat16(tile[k32l * 32 + quad * 8 + j][col]);
        int k32 = kt * 2 + k32l;
        *(v8s*)(dst + (size_t)(h16 * 32 + k32) * 512 + l * 8) = *(v8s*)o;
    }
}

// ---------------------------------------------------------------------------
__device__ __forceinline__ void spinwait(const int* p, int target) {
    while (__hip_atomic_load(p, __ATOMIC_RELAXED, __HIP_MEMORY_SCOPE_AGENT) < target)
        __builtin_amdgcn_s_sleep(1);
}

// One layer's 64-step recurrence. Block: 256 batch x 32 cols (8 h x 4 gates).
// Weights in LDS, c-state in registers. K-loop rotated per block (de-convoy:
// same-XCD blocks start at different K-groups so L3 misses spread and L2 hits
// dominate), grouped double-buffered A-prefetch with sched_barrier pin.
template<int LAYER>
__device__ __forceinline__ void run_layer(
    bf16* __restrict__ S1, bf16* __restrict__ S2,
    bf16* __restrict__ h2fin,
    const bf16* __restrict__ Bl,
    bf16* __restrict__ hstage,
    const float* __restrict__ bias,
    int hb,
    int* __restrict__ flags1, int* __restrict__ flags2)
{
    constexpr int NT = LAYER ? 64 : 48;
    constexpr int G = 8, NG = NT / G;
    bf16* __restrict__ S = LAYER ? S2 : S1;
    const size_t STR = LAYER ? STR2 : STR1;
    int* pub = LAYER ? flags2 : flags1;

    const int tid = threadIdx.x;
    const int lane = tid & 63, wave = tid >> 6;
    const int col = lane & 15, quad = lane >> 4;
    const bool hicol = (col & 8) != 0;
    const int K32 = hb >> 2, Q = hb & 3;
    const int goff = (blockIdx.x >> 3) % NG;

    const float bI = bias[0 * 1024 + hb * 8 + (col & 7)];
    const float bF = bias[1 * 1024 + hb * 8 + (col & 7)];
    const float bG = bias[2 * 1024 + hb * 8 + (col & 7)];
    const float bO = bias[3 * 1024 + hb * 8 + (col & 7)];

    float cc[4] = {0.f, 0.f, 0.f, 0.f};   // cell state in registers, all 64 steps

    const bf16* bl0 = Bl + lane * 8;
    const bf16* bl1 = Bl + (size_t)NT * 512 + lane * 8;

    for (int t = 0; t < SEQ; t++) {
        if (tid == 0) {
            if (LAYER) {
                spinwait(flags1 + t * 64, 128);
                if (t > 0) spinwait(flags2 + (t - 1) * 64, 128);
            } else {
                if (t > 0) spinwait(flags1 + (t - 1) * 64, 128);
            }
        }
        __syncthreads();

        const bf16* a0 = S + (size_t)t * STR + (size_t)((wave * 2 + 0) * NT) * 512 + lane * 8;
        const bf16* a1 = S + (size_t)t * STR + (size_t)((wave * 2 + 1) * NT) * 512 + lane * 8;

        v4f acc[2][2] = {};
        v8s bufA[2][G][2];     // ping-pong group buffers — the register ring

#define LOADG(KB, PP) do {                                                      \
    _Pragma("unroll")                                                           \
    for (int j_ = 0; j_ < G; j_++) {                                            \
        bufA[PP][j_][0] = *(const v8s*)(a0 + (size_t)((KB) + j_) * 512);        \
        bufA[PP][j_][1] = *(const v8s*)(a1 + (size_t)((KB) + j_) * 512);        \
    }                                                                           \
} while (0)

        int kbn = goff * G;
        LOADG(kbn, 0);

#pragma unroll
        for (int gi = 0; gi < NG; gi++) {
            const int pp = gi & 1;
            const int kbc = kbn;
            if (gi + 1 < NG) {
                int gq = gi + 1 + goff; if (gq >= NG) gq -= NG;
                kbn = gq * G;
                LOADG(kbn, pp ^ 1);
            }
            __builtin_amdgcn_sched_barrier(0);   // pin: prefetch issues first
#pragma unroll
            for (int j = 0; j < G; j++) {
                const int k = kbc + j;
                v8s b0 = *(const v8s*)(bl0 + (size_t)k * 512);
                v8s b1 = *(const v8s*)(bl1 + (size_t)k * 512);
                acc[0][0] = __builtin_amdgcn_mfma_f32_16x16x32_bf16(bufA[pp][j][0], b0, acc[0][0], 0, 0, 0);
                acc[0][1] = __builtin_amdgcn_mfma_f32_16x16x32_bf16(bufA[pp][j][0], b1, acc[0][1], 0, 0, 0);
                acc[1][0] = __builtin_amdgcn_mfma_f32_16x16x32_bf16(bufA[pp][j][1], b0, acc[1][0], 0, 0, 0);
                acc[1][1] = __builtin_amdgcn_mfma_f32_16x16x32_bf16(bufA[pp][j][1], b1, acc[1][1], 0, 0, 0);
            }
        }
#undef LOADG

        // ---- epilogue: lane^8 gate exchange, register cell, LDS h-transpose ----
#pragma unroll
        for (int r = 0; r < 4; r++) {
            float send0 = hicol ? acc[0][0][r] : acc[1][0][r];
            float send1 = hicol ? acc[0][1][r] : acc[1][1][r];
            float recv0 = __shfl_xor(send0, 8, 64);
            float recv1 = __shfl_xor(send1, 8, 64);
            float own0 = hicol ? acc[1][0][r] : acc[0][0][r];
            float own1 = hicol ? acc[1][1][r] : acc[0][1][r];
            float zi = (hicol ? recv0 : own0) + bI;
            float zf = (hicol ? own0 : recv0) + bF;
            float zg = (hicol ? recv1 : own1) + bG;
            float zo = (hicol ? own1 : recv1) + bO;
            float ig = 1.f / (1.f + __expf(-zi));
            float fg = 1.f / (1.f + __expf(-zf));
            float e2g = __expf(2.f * zg);
            float gg = (e2g - 1.f) / (e2g + 1.f);
            float og = 1.f / (1.f + __expf(-zo));
            float cn = fg * cc[r] + ig * gg;
            float e2c = __expf(2.f * cn);
            float th = (e2c - 1.f) / (e2c + 1.f);
            cc[r] = cn;
            int m_local = wave * 32 + (hicol ? 16 : 0) + quad * 4 + r;
            hstage[m_local * 8 + (col & 7)] = __float2bfloat16(og * th);
        }
        // flush: lanes 0..31 emit one m-row (8 h = 16 B) into consumer staging,
        // write-through (sc0 sc1) so data reaches the coherence point.
        if (lane < 32) {
            int row = wave * 32 + lane;
            v8s hv = *(const v8s*)(hstage + row * 8);
            u64 qq[2];
            *(v8s*)qq = hv;
            const size_t inner = (size_t)((row & 15) + 16 * Q) * 8;
            const int m16 = row >> 4;
            if (LAYER == 0) {
                // h1(t) -> S2[t] chunk K32   (L2 consumes at step t)
                u64* dB = (u64*)(S2 + (size_t)t * STR2
                                 + (size_t)(m16 * 64 + K32) * 512 + inner);
                __hip_atomic_store(dB,     qq[0], __ATOMIC_RELAXED, __HIP_MEMORY_SCOPE_AGENT);
                __hip_atomic_store(dB + 1, qq[1], __ATOMIC_RELAXED, __HIP_MEMORY_SCOPE_AGENT);
                // h1(t) -> S1[t+1] chunk 16+K32  (own layer next step)
                if (t < 63) {
                    u64* dA = (u64*)(S1 + (size_t)(t + 1) * STR1
                                     + (size_t)(m16 * 48 + 16 + K32) * 512 + inner);
                    __hip_atomic_store(dA,     qq[0], __ATOMIC_RELAXED, __HIP_MEMORY_SCOPE_AGENT);
                    __hip_atomic_store(dA + 1, qq[1], __ATOMIC_RELAXED, __HIP_MEMORY_SCOPE_AGENT);
                }
            } else {
                if (t < 63) {
                    // h2(t) -> S2[t+1] chunk 32+K32
                    u64* dA = (u64*)(S2 + (size_t)(t + 1) * STR2
                                     + (size_t)(m16 * 64 + 32 + K32) * 512 + inner);
                    __hip_atomic_store(dA,     qq[0], __ATOMIC_RELAXED, __HIP_MEMORY_SCOPE_AGENT);
                    __hip_atomic_store(dA + 1, qq[1], __ATOMIC_RELAXED, __HIP_MEMORY_SCOPE_AGENT);
                } else {
                    // final h2 -> h2fin (proj input, [m16][k32(32)][512])
                    u64* dA = (u64*)(h2fin + (size_t)(m16 * 32 + K32) * 512 + inner);
                    __hip_atomic_store(dA,     qq[0], __ATOMIC_RELAXED, __HIP_MEMORY_SCOPE_AGENT);
                    __hip_atomic_store(dA + 1, qq[1], __ATOMIC_RELAXED, __HIP_MEMORY_SCOPE_AGENT);
                }
            }
        }
        __syncthreads();   // all waves drain vmcnt before publish

        if (tid == 0)
            __hip_atomic_fetch_add(pub + t * 64, 1,
                                   __ATOMIC_RELAXED, __HIP_MEMORY_SCOPE_AGENT);
    }
}

__global__ __launch_bounds__(512, 2) void lstm_persist(
    bf16* __restrict__ S1, bf16* __restrict__ S2,
    bf16* __restrict__ h2fin,
    const bf16* __restrict__ Bf1, const bf16* __restrict__ Bf2,
    const float* __restrict__ b1, const float* __restrict__ b2,
    int* __restrict__ flags1, int* __restrict__ flags2)
{
    extern __shared__ char smem[];
    bf16* Bl = (bf16*)smem;
    bf16* hstage = (bf16*)(smem + 131072);

    const int b = blockIdx.x;
    const int layer = b >> 7;
    const int hb = b & 127;
    const int tid = threadIdx.x;

    // one-time weight slice -> LDS (96 KB L1 / 128 KB L2)
    {
        const int NTl = layer ? 64 : 48;
        const bf16* Bsrc = (layer ? Bf2 : Bf1) + (size_t)(hb * 2 * NTl) * 512;
        const int nbytes = NTl * 2 * 1024;
        for (int o = tid * 16; o < nbytes; o += 512 * 16)
            *(uint4*)(smem + o) = *(const uint4*)((const char*)Bsrc + o);
    }
    __syncthreads();

    if (layer == 0)
        run_layer<0>(S1, S2, h2fin, Bl, hstage, b1, hb, flags1, flags2);
    else
        run_layer<1>(S1, S2, h2fin, Bl, hstage, b2, hb, flags1, flags2);
}

// ---------------- projection: out = h2(63) @ Wo + bo ----------------
__global__ __launch_bounds__(256, 2) void proj_kernel(
    const bf16* __restrict__ H,
    const bf16* __restrict__ Wof,
    const float* __restrict__ bo,
    float* __restrict__ Out)
{
    const int mblk = blockIdx.x, nblk = blockIdx.y;
    const int tid = threadIdx.x;
    const int lane = tid & 63;
    const int wave = tid >> 6;
    const int mw = wave >> 1, nw = wave & 1;
    const int col = lane & 15, quad = lane >> 4;

    const int m16 = mblk * 4 + mw * 2;
    const bf16* ah0 = H + (size_t)(m16 * 32) * 512 + lane * 8;
    const bf16* ah1 = H + (size_t)((m16 + 1) * 32) * 512 + lane * 8;
    const int n16a = nblk * 4 + nw * 2, n16b = n16a + 1;
    const bf16* bb0 = Wof + (size_t)(n16a * 32) * 512 + lane * 8;
    const bf16* bb1 = Wof + (size_t)(n16b * 32) * 512 + lane * 8;

    v4f acc00{}, acc01{}, acc10{}, acc11{};
    v8s ra0[8], ra1[8], rb0[8], rb1[8];

#define ISSUE(KK, SLOT) do {                          \
    const int kk_ = (KK);                             \
    ra0[SLOT] = *(const v8s*)(ah0 + kk_ * 512);       \
    ra1[SLOT] = *(const v8s*)(ah1 + kk_ * 512);       \
    rb0[SLOT] = *(const v8s*)(bb0 + kk_ * 512);       \
    rb1[SLOT] = *(const v8s*)(bb1 + kk_ * 512);       \
} while (0)

#pragma unroll
    for (int u = 0; u < 8; u++) ISSUE(u, u);

    for (int base = 0; base < 32; base += 8) {
#pragma unroll
        for (int u = 0; u < 8; u++) {
            acc00 = __builtin_amdgcn_mfma_f32_16x16x32_bf16(ra0[u], rb0[u], acc00, 0, 0, 0);
            acc01 = __builtin_amdgcn_mfma_f32_16x16x32_bf16(ra0[u], rb1[u], acc01, 0, 0, 0);
            acc10 = __builtin_amdgcn_mfma_f32_16x16x32_bf16(ra1[u], rb0[u], acc10, 0, 0, 0);
            acc11 = __builtin_amdgcn_mfma_f32_16x16x32_bf16(ra1[u], rb1[u], acc11, 0, 0, 0);
            const int k2 = base + u + 8;
            if (k2 < 32) ISSUE(k2, u);
        }
    }
#undef ISSUE

    const int n0 = n16a * 16 + col, n1 = n16b * 16 + col;
    const float bo0 = (n0 < CLASSES) ? bo[n0] : 0.f;
    const float bo1 = (n1 < CLASSES) ? bo[n1] : 0.f;
#pragma unroll
    for (int i = 0; i < 2; i++) {
        const int row = mblk * 64 + mw * 32 + i * 16 + quad * 4;
        v4f a0 = i ? acc10 : acc00;
        v4f a1 = i ? acc11 : acc01;
#pragma unroll
        for (int r = 0; r < 4; r++) {
            if (n0 < CLASSES) Out[(size_t)(row + r) * CLASSES + n0] = a0[r] + bo0;
            if (n1 < CLASSES) Out[(size_t)(row + r) * CLASSES + n1] = a1[r] + bo1;
        }
    }
}

// ---------------- launcher ----------------
extern "C" void kernel_launch(void* const* d_in, const int* in_sizes, int n_in,
                              void* d_out, int out_size, void* d_ws, size_t ws_size,
                              hipStream_t stream) {
    const float* x  = (const float*)d_in[0];
    const float* W1 = (const float*)d_in[1];
    const float* U1 = (const float*)d_in[2];
    const float* b1 = (const float*)d_in[3];
    const float* W2 = (const float*)d_in[4];
    const float* U2 = (const float*)d_in[5];
    const float* b2 = (const float*)d_in[6];
    const float* Wo = (const float*)d_in[7];
    const float* bo = (const float*)d_in[8];
    float* out = (float*)d_out;

    char* ws = (char*)d_ws;
    size_t off = 0;
    auto alloc = [&](size_t bytes) -> void* {
        void* p = ws + off;
        off += (bytes + 255) & ~(size_t)255;
        return p;
    };
    bf16* S1    = (bf16*)alloc((size_t)SEQ * STR1 * 2);            // 50.3 MB
    bf16* S2    = (bf16*)alloc((size_t)SEQ * STR2 * 2);            // 67.1 MB
    bf16* Bf1   = (bf16*)alloc((size_t)128 * 2 * 48 * 512 * 2);    // 12.6 MB
    bf16* Bf2   = (bf16*)alloc((size_t)128 * 2 * 64 * 512 * 2);    // 16.8 MB
    bf16* Wof   = (bf16*)alloc((size_t)64 * 32 * 512 * 2);         // 2 MB
    bf16* h2fin = (bf16*)alloc((size_t)BATCH * HIDDEN * 2);        // 0.5 MB
    int* flags1 = (int*)alloc(64 * 64 * 4);
    int* flags2 = (int*)alloc(64 * 64 * 4);

    // zero step-0 staging (h(-1) = 0); conv_x then fills the x slots of S1[0]
    hipMemsetAsync(S1, 0, STR1 * 2, stream);
    hipMemsetAsync(S2, 0, STR2 * 2, stream);
    hipMemsetAsync(flags1, 0, 64 * 64 * 4, stream);
    hipMemsetAsync(flags2, 0, 64 * 64 * 4, stream);

    conv_x<<<4096, 256, 0, stream>>>(x, S1);
    // Bf1 K-order: x-part (W1, 16 chunks) then h1-part (U1, 32)  == S1
    build_bf<<<dim3(24, 128, 2), 256, 0, stream>>>(W1, U1, 512, 48, Bf1);
    // Bf2 K-order: h1-part (W2, 32 chunks) then h2-part (U2, 32) == S2
    build_bf<<<dim3(32, 128, 2), 256, 0, stream>>>(W2, U2, 1024, 64, Bf2);
    build_wof<<<dim3(16, 64), 256, 0, stream>>>(Wo, Wof);

    lstm_persist<<<256, 512, 135168, stream>>>(S1, S2, h2fin, Bf1, Bf2,
                                               b1, b2, flags1, flags2);

    proj_kernel<<<dim3(4, 16), 256, 0, stream>>>(h2fin, Wof, bo, out);
}